// Round 1
// baseline (410.113 us; speedup 1.0000x reference)
//
#include <hip/hip_runtime.h>
#include <hip/hip_bf16.h>
#include <math.h>

// Problem constants
#define BATCH 8
#define SEQ   2048
#define DMODEL 1024
#define GROUPS 2
#define VOCAB 320            // codebook size per group
#define NOUT  (GROUPS*VOCAB) // 640
#define DG    (DMODEL/GROUPS) // 512
#define NTOK  (BATCH*SEQ)    // 16384
#define NTILES (NOUT/64)     // 10 column tiles of 64

// GEMM tiling
#define BM 128
#define BN 64
#define BK 16
#define TM 8
#define TN 4

// Kernel 1: logits = X @ W^T + b, fused per-tile argmax.
// Writes per (token, col-tile) the (max, global_col_idx) candidate.
__global__ __launch_bounds__(256) void logits_argmax_kernel(
    const float* __restrict__ X,     // [NTOK][DMODEL]
    const float* __restrict__ W,     // [NOUT][DMODEL]
    const float* __restrict__ bias,  // [NOUT]
    float* __restrict__ tile_val,    // [NTOK][NTILES]
    int*   __restrict__ tile_idx)    // [NTOK][NTILES]
{
    __shared__ __align__(16) float As[BK][BM];  // 16x128 = 8 KB
    __shared__ __align__(16) float Bs[BK][BN];  // 16x64  = 4 KB

    const int tid = threadIdx.x;
    const int tx = tid & 15;        // 0..15 -> 4 cols each
    const int ty = tid >> 4;        // 0..15 -> 8 rows each
    const int m0 = blockIdx.x * BM; // token tile base
    const int n0 = blockIdx.y * BN; // output tile base

    float acc[TM][TN];
    #pragma unroll
    for (int r = 0; r < TM; r++)
        #pragma unroll
        for (int c = 0; c < TN; c++)
            acc[r][c] = 0.0f;

    const float* Xp = X + (size_t)m0 * DMODEL;
    const float* Wp = W + (size_t)n0 * DMODEL;

    for (int k0 = 0; k0 < DMODEL; k0 += BK) {
        // Stage A tile (128 rows x 16 cols) transposed into As[k][m].
        // 512 float4 total, 2 per thread.
        #pragma unroll
        for (int i = 0; i < 2; i++) {
            int f = tid + i * 256;          // 0..511
            int row = f >> 2;               // 0..127
            int quad = f & 3;               // 0..3
            float4 v = *(const float4*)(Xp + row * DMODEL + k0 + quad * 4);
            As[quad * 4 + 0][row] = v.x;
            As[quad * 4 + 1][row] = v.y;
            As[quad * 4 + 2][row] = v.z;
            As[quad * 4 + 3][row] = v.w;
        }
        // Stage B tile (64 rows x 16 cols) transposed into Bs[k][n].
        {
            int row = tid >> 2;             // 0..63
            int quad = tid & 3;
            float4 v = *(const float4*)(Wp + row * DMODEL + k0 + quad * 4);
            Bs[quad * 4 + 0][row] = v.x;
            Bs[quad * 4 + 1][row] = v.y;
            Bs[quad * 4 + 2][row] = v.z;
            Bs[quad * 4 + 3][row] = v.w;
        }
        __syncthreads();

        #pragma unroll
        for (int kk = 0; kk < BK; kk++) {
            float a[TM], bv[TN];
            *(float4*)&a[0] = *(const float4*)&As[kk][ty * TM];
            *(float4*)&a[4] = *(const float4*)&As[kk][ty * TM + 4];
            *(float4*)&bv[0] = *(const float4*)&Bs[kk][tx * TN];
            #pragma unroll
            for (int r = 0; r < TM; r++)
                #pragma unroll
                for (int c = 0; c < TN; c++)
                    acc[r][c] = fmaf(a[r], bv[c], acc[r][c]);
        }
        __syncthreads();
    }

    // Bias add + per-token argmax over this 64-column tile.
    float bb[TN];
    *(float4*)&bb[0] = *(const float4*)(bias + n0 + tx * TN);

    #pragma unroll
    for (int r = 0; r < TM; r++) {
        float best = acc[r][0] + bb[0];
        int bi = tx * TN;
        #pragma unroll
        for (int c = 1; c < TN; c++) {
            float v = acc[r][c] + bb[c];
            if (v > best) { best = v; bi = tx * TN + c; }   // strict > : first max wins
        }
        // Reduce across the 16 lanes that share ty (they are lanes with equal tid>>4 within the wave).
        #pragma unroll
        for (int off = 1; off < 16; off <<= 1) {
            float ov = __shfl_xor(best, off);
            int   oi = __shfl_xor(bi, off);
            if (ov > best || (ov == best && oi < bi)) { best = ov; bi = oi; }
        }
        if (tx == 0) {
            int token = m0 + ty * TM + r;
            tile_val[token * NTILES + blockIdx.y] = best;
            tile_idx[token * NTILES + blockIdx.y] = n0 + bi;  // global column
        }
    }
}

// Kernel 2: per (token, group): reduce 5 tile candidates -> final argmax,
// write idx (as float), histogram count, gather codevector row to out.
__global__ __launch_bounds__(256) void select_gather_kernel(
    const float* __restrict__ tile_val,
    const int*   __restrict__ tile_idx,
    const float* __restrict__ cb,      // [NOUT][DG]
    float* __restrict__ out,           // [NTOK][DMODEL]
    float* __restrict__ out_idx,       // [NTOK*GROUPS] flat (b,s,g) order
    int*   __restrict__ hist)          // [NOUT]
{
    const int wave = threadIdx.x >> 6;          // 0..3
    const int lane = threadIdx.x & 63;
    const int tg = blockIdx.x * 4 + wave;       // 0..32767
    const int token = tg >> 1;
    const int g = tg & 1;

    // All lanes redundantly reduce the 5 candidates (broadcast loads).
    const float* tv = tile_val + token * NTILES + g * 5;
    const int*   ti = tile_idx + token * NTILES + g * 5;
    float best = tv[0];
    int bi = ti[0];
    #pragma unroll
    for (int t = 1; t < 5; t++) {
        float v = tv[t];
        if (v > best) { best = v; bi = ti[t]; }  // tiles ascending in idx: strict > keeps first max
    }
    const int idx = bi - g * VOCAB;              // within-group index 0..319

    if (lane == 0) {
        out_idx[token * GROUPS + g] = (float)idx;
        atomicAdd(&hist[g * VOCAB + idx], 1);
    }

    // Copy the selected codevector row (512 floats) with float4s.
    const float4* src = (const float4*)(cb + (size_t)(g * VOCAB + idx) * DG);
    float4* dst = (float4*)(out + (size_t)token * DMODEL + g * DG);
    dst[lane]      = src[lane];
    dst[lane + 64] = src[lane + 64];
}

// Kernel 3: diversity loss scalar from the histogram.
__global__ __launch_bounds__(256) void diversity_kernel(
    const int* __restrict__ hist, float* __restrict__ out_scalar)
{
    __shared__ float s0[256], s1[256];
    const int tid = threadIdx.x;
    float a0 = 0.0f, a1 = 0.0f;
    for (int i = tid; i < NOUT; i += 256) {
        float m = (float)hist[i] * (1.0f / (float)NTOK);
        float t = m * logf(m + 1e-7f);
        if (i < VOCAB) a0 += t; else a1 += t;
    }
    s0[tid] = a0; s1[tid] = a1;
    __syncthreads();
    for (int s = 128; s > 0; s >>= 1) {
        if (tid < s) { s0[tid] += s0[tid + s]; s1[tid] += s1[tid + s]; }
        __syncthreads();
    }
    if (tid == 0) {
        float perplexity = expf(-s0[0]) + expf(-s1[0]);
        *out_scalar = ((float)NOUT - perplexity) / (float)NOUT * 0.1f;
    }
}

extern "C" void kernel_launch(void* const* d_in, const int* in_sizes, int n_in,
                              void* d_out, int out_size, void* d_ws, size_t ws_size,
                              hipStream_t stream) {
    const float* X    = (const float*)d_in[0];  // hidden_states [8,2048,1024]
    const float* W    = (const float*)d_in[1];  // [640,1024]
    const float* bias = (const float*)d_in[2];  // [640]
    const float* cb   = (const float*)d_in[3];  // [1,640,512]

    float* out      = (float*)d_out;                 // [16384*1024]
    float* out_idx  = out + (size_t)NTOK * DMODEL;   // [32768]
    float* out_loss = out_idx + (size_t)NTOK * GROUPS; // [1]

    // Workspace layout: tile_val (640 KB) | tile_idx (640 KB) | hist (2.5 KB)
    float* tile_val = (float*)d_ws;
    int*   tile_idx = (int*)((char*)d_ws + (size_t)NTOK * NTILES * 4);
    int*   hist     = (int*)((char*)d_ws + (size_t)NTOK * NTILES * 8);

    hipMemsetAsync(hist, 0, NOUT * sizeof(int), stream);

    dim3 gridA(NTOK / BM, NTILES);   // 128 x 10
    logits_argmax_kernel<<<gridA, 256, 0, stream>>>(X, W, bias, tile_val, tile_idx);

    select_gather_kernel<<<(NTOK * GROUPS) / 4, 256, 0, stream>>>(
        tile_val, tile_idx, cb, out, out_idx, hist);

    diversity_kernel<<<1, 256, 0, stream>>>(hist, out_loss);
}